// Round 2
// baseline (86.235 us; speedup 1.0000x reference)
//
#include <hip/hip_runtime.h>

// LFQ quantizer, factorized softmax. FP32 in / FP32 out.
// N=8192 samples (8x1024), D=14 dims, K=16384 codes, T=0.01, EPS=1e-5.
// Softmax over 2^14 codes factorizes into 14 independent Bernoullis:
//   per-dim flip weight t_d = exp(-400*|x_d|);  Z = prod_d (1+t_d)
//   sample_entropy = sum_d [log(1+t_d) + v_d*t_d/(1+t_d)],  v_d = 400*|x_d|
// avg_probs histogram: scatter base * prod(t over flipped soft dims) for all
// subsets of "soft" dims (t > 1e-7); neglected mass < 1.4e-5 total.

#define N_SAMPLES 8192
#define DIMS      14
#define KCODES    16384
#define LFQ_EPS   1e-5f

// ws layout: [0..K-1] avg_probs accumulator (sum of per-sample probs),
//            [K] commit-loss sum, [K+1] sample-entropy sum
__global__ void __launch_bounds__(256)
lfq_main(const float* __restrict__ x,
         float* __restrict__ qout,
         float* __restrict__ avgp,
         float* __restrict__ acc)
{
    const int i = blockIdx.x * 256 + threadIdx.x;   // sample id, grid == N_SAMPLES
    float commit = 0.f, sampH = 0.f;

    const float* xp = x + (size_t)i * DIMS;
    float* qp = qout + (size_t)i * DIMS;

    int code = 0;
    float sumLog = 0.f;                 // sum_d log(1+t_d) = log Z
    int   softd[DIMS];
    float softt[DIMS];
    int   S = 0;

#pragma unroll
    for (int d = 0; d < DIMS; ++d) {
        float xv = xp[d];
        bool pos = xv > 0.f;
        float q = pos ? 1.f : -1.f;
        qp[d] = q;
        float diff = xv - q;
        commit += diff * diff;
        code |= (pos ? 1 : 0) << d;

        float v = 400.f * fabsf(xv);    // logit gap to flipped bit
        float t = __expf(-v);           // flip weight, in (0,1]
        float l1p = log1pf(t);
        sumLog += l1p;
        // Bernoulli entropy: log(1+t) + v*t/(1+t)
        sampH += l1p + v * t / (1.f + t);
        if (t > 1e-7f) { softd[S] = d; softt[S] = t; ++S; }
    }

    // scatter per-sample probabilities: subsets of soft dims carry all
    // non-negligible mass. base = 1/Z.
    float base = __expf(-sumLog);
    int nsub = 1 << S;
    for (int m = 0; m < nsub; ++m) {
        float mass = base;
        int c = code;
        for (int k = 0; k < S; ++k) {
            if ((m >> k) & 1) { mass *= softt[k]; c ^= 1 << softd[k]; }
        }
        if (mass > 1e-12f) atomicAdd(&avgp[c], mass);
    }

    // wave-level reduce (64 lanes), one atomic per wave
    for (int off = 32; off > 0; off >>= 1) {
        commit += __shfl_down(commit, off);
        sampH  += __shfl_down(sampH,  off);
    }
    if ((threadIdx.x & 63) == 0) {
        atomicAdd(&acc[0], commit);
        atomicAdd(&acc[1], sampH);
    }
}

__global__ void __launch_bounds__(256)
lfq_final(const float* __restrict__ avgp,
          const float* __restrict__ acc,
          float* __restrict__ out)
{
    __shared__ float red[256];
    float e = 0.f;
    for (int j = threadIdx.x; j < KCODES; j += 256) {
        float a = avgp[j] * (1.f / (float)N_SAMPLES);
        e -= a * logf(a + LFQ_EPS);     // a==0 contributes exactly 0
    }
    red[threadIdx.x] = e;
    __syncthreads();
    for (int s = 128; s > 0; s >>= 1) {
        if (threadIdx.x < s) red[threadIdx.x] += red[threadIdx.x + s];
        __syncthreads();
    }
    if (threadIdx.x == 0) {
        float avgH    = red[0];
        float sampleH = acc[1] * (1.f / (float)N_SAMPLES);
        float commit  = acc[0] * (1.f / (float)(N_SAMPLES * DIMS));
        float aux     = sampleH - avgH;   // SAMPLE_MIN_W=1, BATCH_MAX_W=1
        out[N_SAMPLES * DIMS + 0] = aux;
        out[N_SAMPLES * DIMS + 1] = sampleH;
        out[N_SAMPLES * DIMS + 2] = avgH;
        out[N_SAMPLES * DIMS + 3] = commit;
    }
}

extern "C" void kernel_launch(void* const* d_in, const int* in_sizes, int n_in,
                              void* d_out, int out_size, void* d_ws, size_t ws_size,
                              hipStream_t stream) {
    const float* x = (const float*)d_in[0];
    float* out = (float*)d_out;
    float* avgp = (float*)d_ws;
    float* acc  = avgp + KCODES;

    hipMemsetAsync(d_ws, 0, (KCODES + 2) * sizeof(float), stream);
    lfq_main<<<N_SAMPLES / 256, 256, 0, stream>>>(x, out, avgp, acc);
    lfq_final<<<1, 256, 0, stream>>>(avgp, acc, out);
}